// Round 9
// baseline (556.731 us; speedup 1.0000x reference)
//
#include <hip/hip_runtime.h>

#define HEAD_NUM 32
#define D_K 128
#define HIDDEN 4096
#define MAX_BS 16
#define MAX_SEQ 2048
#define NCHUNK 8        // seq chunks for flash-decoding split
#define CHUNK 256       // MAX_SEQ / NCHUNK

// ---------------------------------------------------------------------------
// Kernel 1: q/k/v = x @ {w_q,w_k,w_v}. Each thread owns 4 consecutive cols
// (float4 weight loads, 16 B/lane). x staged in LDS; read as float4 windows
// (one ds_read_b128 per batch per 4-ii window -> DS pipe cost /4 vs R2,
// which was the ~3.3 TB/s GEMV ceiling). k-split x64; atomics into zeroed qkv.
// Grid (4 colTiles x 64 kChunks x 3 mats) = 768 blocks.
// ---------------------------------------------------------------------------
__global__ __launch_bounds__(256) void qkv_kernel(
    const float* __restrict__ x,
    const float* __restrict__ w_q,
    const float* __restrict__ w_k,
    const float* __restrict__ w_v,
    float* __restrict__ qkv)     // [3][MAX_BS][HIDDEN], pre-zeroed
{
    __shared__ float xs[MAX_BS][64];
    const int colTile = blockIdx.x;   // 0..3  (1024 cols each)
    const int kChunk  = blockIdx.y;   // 0..63 (64 k each)
    const int mat     = blockIdx.z;   // 0..2
    const int tid     = threadIdx.x;

    const float* W = (mat == 0) ? w_q : (mat == 1) ? w_k : w_v;
    float* outp = qkv + (size_t)mat * (MAX_BS * HIDDEN);

    {   // stage x[16][64]: 256 float4, one per thread (coalesced per row)
        const int b = tid >> 4;
        const int f = tid & 15;
        *reinterpret_cast<float4*>(&xs[b][f * 4]) =
            *reinterpret_cast<const float4*>(&x[b * HIDDEN + kChunk * 64 + f * 4]);
    }
    __syncthreads();

    const int col = colTile * 1024 + tid * 4;   // 4 consecutive cols/thread
    const int k0  = kChunk * 64;

    float4 acc[MAX_BS];
    #pragma unroll
    for (int b = 0; b < MAX_BS; ++b) acc[b] = make_float4(0.f, 0.f, 0.f, 0.f);

    const float* wbase = W + (size_t)k0 * HIDDEN + col;
    for (int w = 0; w < 64; w += 4) {          // 16 windows of 4 k-rows
        const float4 w0 = *reinterpret_cast<const float4*>(&wbase[(size_t)(w + 0) * HIDDEN]);
        const float4 w1 = *reinterpret_cast<const float4*>(&wbase[(size_t)(w + 1) * HIDDEN]);
        const float4 w2 = *reinterpret_cast<const float4*>(&wbase[(size_t)(w + 2) * HIDDEN]);
        const float4 w3 = *reinterpret_cast<const float4*>(&wbase[(size_t)(w + 3) * HIDDEN]);
        #pragma unroll
        for (int b = 0; b < MAX_BS; ++b) {
            const float4 xv = *reinterpret_cast<const float4*>(&xs[b][w]);  // ds_read_b128 broadcast
            acc[b].x = fmaf(xv.x, w0.x, fmaf(xv.y, w1.x, fmaf(xv.z, w2.x, fmaf(xv.w, w3.x, acc[b].x))));
            acc[b].y = fmaf(xv.x, w0.y, fmaf(xv.y, w1.y, fmaf(xv.z, w2.y, fmaf(xv.w, w3.y, acc[b].y))));
            acc[b].z = fmaf(xv.x, w0.z, fmaf(xv.y, w1.z, fmaf(xv.z, w2.z, fmaf(xv.w, w3.z, acc[b].z))));
            acc[b].w = fmaf(xv.x, w0.w, fmaf(xv.y, w1.w, fmaf(xv.z, w2.w, fmaf(xv.w, w3.w, acc[b].w))));
        }
    }

    #pragma unroll
    for (int b = 0; b < MAX_BS; ++b) {
        atomicAdd(&outp[b * HIDDEN + col + 0], acc[b].x);
        atomicAdd(&outp[b * HIDDEN + col + 1], acc[b].y);
        atomicAdd(&outp[b * HIDDEN + col + 2], acc[b].z);
        atomicAdd(&outp[b * HIDDEN + col + 3], acc[b].w);
    }
}

// ---------------------------------------------------------------------------
// Kernel 2: flash-decoding partials (verbatim from R6). 16 groups x 16 lanes,
// fixed 256-row trip; new-token row masked to -INF (handled in combine).
// ---------------------------------------------------------------------------
__global__ __launch_bounds__(256) void attn_partial_kernel(
    const float* __restrict__ cache_k,
    const float* __restrict__ cache_v,
    const float* __restrict__ qkv,
    const int*   __restrict__ start_pos_p,
    float* __restrict__ part_o,    // [B][H][NCHUNK][D_K]
    float* __restrict__ part_ml)   // [B][H][NCHUNK][2]
{
    const int h   = blockIdx.x;
    const int b   = blockIdx.y;
    const int c   = blockIdx.z;
    const int tid = threadIdx.x;
    const int start_pos = *start_pos_p;
    const int s0        = c * CHUNK;

    __shared__ float sc[CHUNK];
    __shared__ float red[8];
    __shared__ float partial[16][D_K];

    const int lane16 = tid & 15;
    const int grp    = tid >> 4;         // 0..15
    const int wid    = tid >> 6;         // 0..3

    const float* q = qkv + b * HIDDEN + h * D_K;
    const float4 q0 = *reinterpret_cast<const float4*>(&q[lane16 * 8]);
    const float4 q1 = *reinterpret_cast<const float4*>(&q[lane16 * 8 + 4]);
    const float scale = 0.08838834764831845f;   // 1/sqrt(128)

    const size_t rowstride = (size_t)HEAD_NUM * D_K;   // 4096 floats
    const float* kbase = cache_k + (((size_t)b * MAX_SEQ + s0) * HEAD_NUM + h) * D_K;
    const float* vbase = cache_v + (((size_t)b * MAX_SEQ + s0) * HEAD_NUM + h) * D_K;

    // ---- phase A: scores -------------------------------------------------
    #pragma unroll 4
    for (int it = 0; it < 16; ++it) {
        const int r = it * 16 + grp;
        const float* krow = kbase + (size_t)r * rowstride + lane16 * 8;
        const float4 k0 = *reinterpret_cast<const float4*>(krow);
        const float4 k1 = *reinterpret_cast<const float4*>(krow + 4);
        float p = q0.x * k0.x + q0.y * k0.y + q0.z * k0.z + q0.w * k0.w
                + q1.x * k1.x + q1.y * k1.y + q1.z * k1.z + q1.w * k1.w;
        p += __shfl_xor(p, 8);
        p += __shfl_xor(p, 4);
        p += __shfl_xor(p, 2);
        p += __shfl_xor(p, 1);
        if (lane16 == 0)
            sc[r] = (s0 + r < start_pos) ? p * scale : -INFINITY;
    }
    __syncthreads();

    // ---- phase B: softmax stats ------------------------------------------
    float m = sc[tid];
    #pragma unroll
    for (int off = 32; off; off >>= 1) m = fmaxf(m, __shfl_xor(m, off));
    if ((tid & 63) == 0) red[wid] = m;
    __syncthreads();
    m = fmaxf(fmaxf(red[0], red[1]), fmaxf(red[2], red[3]));

    const float raw = sc[tid];
    const float e = (raw == -INFINITY) ? 0.f : __expf(raw - m);
    __syncthreads();
    sc[tid] = e;
    float sum = e;
    #pragma unroll
    for (int off = 32; off; off >>= 1) sum += __shfl_xor(sum, off);
    if ((tid & 63) == 0) red[4 + wid] = sum;
    __syncthreads();
    sum = red[4] + red[5] + red[6] + red[7];

    // ---- phase C: unnormalized PV ----------------------------------------
    float4 a0 = {0.f, 0.f, 0.f, 0.f};
    float4 a1 = {0.f, 0.f, 0.f, 0.f};
    #pragma unroll 4
    for (int it = 0; it < 16; ++it) {
        const int r = it * 16 + grp;
        const float* vrow = vbase + (size_t)r * rowstride + lane16 * 8;
        const float4 v0 = *reinterpret_cast<const float4*>(vrow);
        const float4 v1 = *reinterpret_cast<const float4*>(vrow + 4);
        const float p = sc[r];
        a0.x = fmaf(p, v0.x, a0.x);  a0.y = fmaf(p, v0.y, a0.y);
        a0.z = fmaf(p, v0.z, a0.z);  a0.w = fmaf(p, v0.w, a0.w);
        a1.x = fmaf(p, v1.x, a1.x);  a1.y = fmaf(p, v1.y, a1.y);
        a1.z = fmaf(p, v1.z, a1.z);  a1.w = fmaf(p, v1.w, a1.w);
    }
    *reinterpret_cast<float4*>(&partial[grp][lane16 * 8])     = a0;
    *reinterpret_cast<float4*>(&partial[grp][lane16 * 8 + 4]) = a1;
    __syncthreads();

    const size_t base = (size_t)(b * HEAD_NUM + h) * NCHUNK + c;
    if (tid < D_K) {
        float r = 0.f;
        #pragma unroll
        for (int g = 0; g < 16; ++g) r += partial[g][tid];
        part_o[base * D_K + tid] = r;
    }
    if (tid == 0) {
        part_ml[base * 2 + 0] = m;
        part_ml[base * 2 + 1] = sum;
    }
}

// ---------------------------------------------------------------------------
// Kernel 3: combine chunk partials + new-token (s = start_pos) term.
// ---------------------------------------------------------------------------
__global__ __launch_bounds__(128) void combine_kernel(
    const float* __restrict__ qkv,
    const float* __restrict__ part_o,
    const float* __restrict__ part_ml,
    float* __restrict__ attn_out)
{
    const int h   = blockIdx.x;
    const int b   = blockIdx.y;
    const int tid = threadIdx.x;     // 0..127
    __shared__ float redS[2];

    const float* q    = qkv + b * HIDDEN + h * D_K;
    const float* knew = qkv + 1 * (MAX_BS * HIDDEN) + b * HIDDEN + h * D_K;
    const float* vnew = qkv + 2 * (MAX_BS * HIDDEN) + b * HIDDEN + h * D_K;

    float pp = q[tid] * knew[tid];
    #pragma unroll
    for (int off = 32; off; off >>= 1) pp += __shfl_xor(pp, off);
    if ((tid & 63) == 0) redS[tid >> 6] = pp;
    __syncthreads();
    const float score = (redS[0] + redS[1]) * 0.08838834764831845f;

    const size_t base = (size_t)(b * HEAD_NUM + h) * NCHUNK;
    float mv[NCHUNK];
    float M = score;
    #pragma unroll
    for (int c = 0; c < NCHUNK; ++c) {
        mv[c] = part_ml[(base + c) * 2];
        M = fmaxf(M, mv[c]);
    }
    float acc = 0.f, l = 0.f;
    #pragma unroll
    for (int c = 0; c < NCHUNK; ++c) {
        const float w = __expf(mv[c] - M);
        acc += w * part_o[(base + c) * D_K + tid];
        l   += w * part_ml[(base + c) * 2 + 1];
    }
    const float wn = __expf(score - M);
    acc += wn * vnew[tid];
    l   += wn;

    attn_out[b * HIDDEN + h * D_K + tid] = acc / l;
}

// ---------------------------------------------------------------------------
// Kernel 4: out = attn_out @ w_o. Same 4-col float4 structure, k-split x128.
// Grid (4 colTiles x 128 kChunks) = 512 blocks.
// ---------------------------------------------------------------------------
__global__ __launch_bounds__(256) void oproj_kernel(
    const float* __restrict__ attn_out,
    const float* __restrict__ w_o,
    float* __restrict__ out)
{
    __shared__ float xs[MAX_BS][32];
    const int colTile = blockIdx.x;   // 0..3
    const int kChunk  = blockIdx.y;   // 0..127 (32 k each)
    const int tid     = threadIdx.x;

    if (tid < 128) {   // stage x[16][32]: 128 float4
        const int b = tid >> 3;
        const int f = tid & 7;
        *reinterpret_cast<float4*>(&xs[b][f * 4]) =
            *reinterpret_cast<const float4*>(&attn_out[b * HIDDEN + kChunk * 32 + f * 4]);
    }
    __syncthreads();

    const int col = colTile * 1024 + tid * 4;
    const int k0  = kChunk * 32;

    float4 acc[MAX_BS];
    #pragma unroll
    for (int b = 0; b < MAX_BS; ++b) acc[b] = make_float4(0.f, 0.f, 0.f, 0.f);

    const float* wbase = w_o + (size_t)k0 * HIDDEN + col;
    for (int w = 0; w < 32; w += 4) {          // 8 windows of 4 k-rows
        const float4 w0 = *reinterpret_cast<const float4*>(&wbase[(size_t)(w + 0) * HIDDEN]);
        const float4 w1 = *reinterpret_cast<const float4*>(&wbase[(size_t)(w + 1) * HIDDEN]);
        const float4 w2 = *reinterpret_cast<const float4*>(&wbase[(size_t)(w + 2) * HIDDEN]);
        const float4 w3 = *reinterpret_cast<const float4*>(&wbase[(size_t)(w + 3) * HIDDEN]);
        #pragma unroll
        for (int b = 0; b < MAX_BS; ++b) {
            const float4 xv = *reinterpret_cast<const float4*>(&xs[b][w]);
            acc[b].x = fmaf(xv.x, w0.x, fmaf(xv.y, w1.x, fmaf(xv.z, w2.x, fmaf(xv.w, w3.x, acc[b].x))));
            acc[b].y = fmaf(xv.x, w0.y, fmaf(xv.y, w1.y, fmaf(xv.z, w2.y, fmaf(xv.w, w3.y, acc[b].y))));
            acc[b].z = fmaf(xv.x, w0.z, fmaf(xv.y, w1.z, fmaf(xv.z, w2.z, fmaf(xv.w, w3.z, acc[b].z))));
            acc[b].w = fmaf(xv.x, w0.w, fmaf(xv.y, w1.w, fmaf(xv.z, w2.w, fmaf(xv.w, w3.w, acc[b].w))));
        }
    }

    #pragma unroll
    for (int b = 0; b < MAX_BS; ++b) {
        atomicAdd(&out[b * HIDDEN + col + 0], acc[b].x);
        atomicAdd(&out[b * HIDDEN + col + 1], acc[b].y);
        atomicAdd(&out[b * HIDDEN + col + 2], acc[b].z);
        atomicAdd(&out[b * HIDDEN + col + 3], acc[b].w);
    }
}

extern "C" void kernel_launch(void* const* d_in, const int* in_sizes, int n_in,
                              void* d_out, int out_size, void* d_ws, size_t ws_size,
                              hipStream_t stream) {
    const float* x       = (const float*)d_in[0];
    const float* cache_k = (const float*)d_in[1];
    const float* cache_v = (const float*)d_in[2];
    const float* w_q     = (const float*)d_in[3];
    const float* w_k     = (const float*)d_in[4];
    const float* w_v     = (const float*)d_in[5];
    const float* w_o     = (const float*)d_in[6];
    const int*   start_pos = (const int*)d_in[7];

    float* out      = (float*)d_out;
    float* qkv      = (float*)d_ws;                          // [3][16][4096]
    float* attn_out = qkv + 3 * MAX_BS * HIDDEN;             // [16][4096]
    float* part_o   = attn_out + MAX_BS * HIDDEN;            // [16][32][8][128]
    float* part_ml  = part_o + (size_t)MAX_BS * HEAD_NUM * NCHUNK * D_K; // [16][32][8][2]

    hipMemsetAsync(qkv, 0, (size_t)3 * MAX_BS * HIDDEN * sizeof(float), stream);
    hipMemsetAsync(d_out, 0, (size_t)out_size * sizeof(float), stream);

    qkv_kernel<<<dim3(4, 64, 3), 256, 0, stream>>>(x, w_q, w_k, w_v, qkv);
    attn_partial_kernel<<<dim3(HEAD_NUM, MAX_BS, NCHUNK), 256, 0, stream>>>(
        cache_k, cache_v, qkv, start_pos, part_o, part_ml);
    combine_kernel<<<dim3(HEAD_NUM, MAX_BS), 128, 0, stream>>>(
        qkv, part_o, part_ml, attn_out);
    oproj_kernel<<<dim3(4, 128), 256, 0, stream>>>(attn_out, w_o, out);
}

// Round 10
// 277.903 us; speedup vs baseline: 2.0033x; 2.0033x over previous
//
#include <hip/hip_runtime.h>

#define HEAD_NUM 32
#define D_K 128
#define HIDDEN 4096
#define MAX_BS 16
#define MAX_SEQ 2048
#define NCHUNK 8        // seq chunks for flash-decoding split
#define CHUNK 256       // MAX_SEQ / NCHUNK

// ---------------------------------------------------------------------------
// Kernel 1: q/k/v = x @ {w_q,w_k,w_v}. R2/R6 structure (1 col/thread,
// 16 scalar acc, k-split x32, atomics into zeroed qkv) with ONE change:
// x is read from LDS as float4 windows (one ds_read_b128 broadcast per
// batch per 4 k-steps) instead of 16 ds_read_b32 per k-step. DS-pipe cost
// per iter drops ~4x; VGPR stays ~30 (acc[16] scalar), occupancy intact.
// ---------------------------------------------------------------------------
__global__ __launch_bounds__(256) void qkv_kernel(
    const float* __restrict__ x,
    const float* __restrict__ w_q,
    const float* __restrict__ w_k,
    const float* __restrict__ w_v,
    float* __restrict__ qkv)     // [3][MAX_BS][HIDDEN], pre-zeroed
{
    __shared__ float xs[MAX_BS][128];
    const int colTile = blockIdx.x;   // 0..15
    const int kChunk  = blockIdx.y;   // 0..31 (128 k each)
    const int mat     = blockIdx.z;   // 0..2
    const int tid     = threadIdx.x;

    const float* W = (mat == 0) ? w_q : (mat == 1) ? w_k : w_v;
    float* outp = qkv + (size_t)mat * (MAX_BS * HIDDEN);

    for (int idx = tid; idx < MAX_BS * 128 / 4; idx += 256) {
        int b = idx >> 5;
        int f = idx & 31;
        *reinterpret_cast<float4*>(&xs[b][f * 4]) =
            *reinterpret_cast<const float4*>(&x[b * HIDDEN + kChunk * 128 + f * 4]);
    }
    __syncthreads();

    const int col = colTile * 256 + tid;
    float acc[MAX_BS];
    #pragma unroll
    for (int b = 0; b < MAX_BS; ++b) acc[b] = 0.f;

    const float* wcol = W + (size_t)(kChunk * 128) * HIDDEN + col;
    #pragma unroll 2
    for (int w = 0; w < 128; w += 4) {         // 32 windows of 4 k-rows
        const float w0 = wcol[(size_t)(w + 0) * HIDDEN];   // coalesced
        const float w1 = wcol[(size_t)(w + 1) * HIDDEN];
        const float w2 = wcol[(size_t)(w + 2) * HIDDEN];
        const float w3 = wcol[(size_t)(w + 3) * HIDDEN];
        #pragma unroll
        for (int b = 0; b < MAX_BS; ++b) {
            const float4 xv = *reinterpret_cast<const float4*>(&xs[b][w]);  // 1 ds_read_b128
            acc[b] = fmaf(xv.x, w0, fmaf(xv.y, w1, fmaf(xv.z, w2, fmaf(xv.w, w3, acc[b]))));
        }
    }

    #pragma unroll
    for (int b = 0; b < MAX_BS; ++b)
        atomicAdd(&outp[b * HIDDEN + col], acc[b]);
}

// ---------------------------------------------------------------------------
// Kernel 2: flash-decoding partials (verbatim R6). 16 groups x 16 lanes,
// fixed 256-row trip; new-token row masked to -INF (handled in combine).
// ---------------------------------------------------------------------------
__global__ __launch_bounds__(256) void attn_partial_kernel(
    const float* __restrict__ cache_k,
    const float* __restrict__ cache_v,
    const float* __restrict__ qkv,
    const int*   __restrict__ start_pos_p,
    float* __restrict__ part_o,    // [B][H][NCHUNK][D_K]
    float* __restrict__ part_ml)   // [B][H][NCHUNK][2]
{
    const int h   = blockIdx.x;
    const int b   = blockIdx.y;
    const int c   = blockIdx.z;
    const int tid = threadIdx.x;
    const int start_pos = *start_pos_p;
    const int s0        = c * CHUNK;

    __shared__ float sc[CHUNK];
    __shared__ float red[8];
    __shared__ float partial[16][D_K];

    const int lane16 = tid & 15;
    const int grp    = tid >> 4;         // 0..15
    const int wid    = tid >> 6;         // 0..3

    const float* q = qkv + b * HIDDEN + h * D_K;
    const float4 q0 = *reinterpret_cast<const float4*>(&q[lane16 * 8]);
    const float4 q1 = *reinterpret_cast<const float4*>(&q[lane16 * 8 + 4]);
    const float scale = 0.08838834764831845f;   // 1/sqrt(128)

    const size_t rowstride = (size_t)HEAD_NUM * D_K;   // 4096 floats
    const float* kbase = cache_k + (((size_t)b * MAX_SEQ + s0) * HEAD_NUM + h) * D_K;
    const float* vbase = cache_v + (((size_t)b * MAX_SEQ + s0) * HEAD_NUM + h) * D_K;

    // ---- phase A: scores -------------------------------------------------
    #pragma unroll 4
    for (int it = 0; it < 16; ++it) {
        const int r = it * 16 + grp;
        const float* krow = kbase + (size_t)r * rowstride + lane16 * 8;
        const float4 k0 = *reinterpret_cast<const float4*>(krow);
        const float4 k1 = *reinterpret_cast<const float4*>(krow + 4);
        float p = q0.x * k0.x + q0.y * k0.y + q0.z * k0.z + q0.w * k0.w
                + q1.x * k1.x + q1.y * k1.y + q1.z * k1.z + q1.w * k1.w;
        p += __shfl_xor(p, 8);
        p += __shfl_xor(p, 4);
        p += __shfl_xor(p, 2);
        p += __shfl_xor(p, 1);
        if (lane16 == 0)
            sc[r] = (s0 + r < start_pos) ? p * scale : -INFINITY;
    }
    __syncthreads();

    // ---- phase B: softmax stats ------------------------------------------
    float m = sc[tid];
    #pragma unroll
    for (int off = 32; off; off >>= 1) m = fmaxf(m, __shfl_xor(m, off));
    if ((tid & 63) == 0) red[wid] = m;
    __syncthreads();
    m = fmaxf(fmaxf(red[0], red[1]), fmaxf(red[2], red[3]));

    const float raw = sc[tid];
    const float e = (raw == -INFINITY) ? 0.f : __expf(raw - m);
    __syncthreads();
    sc[tid] = e;
    float sum = e;
    #pragma unroll
    for (int off = 32; off; off >>= 1) sum += __shfl_xor(sum, off);
    if ((tid & 63) == 0) red[4 + wid] = sum;
    __syncthreads();
    sum = red[4] + red[5] + red[6] + red[7];

    // ---- phase C: unnormalized PV ----------------------------------------
    float4 a0 = {0.f, 0.f, 0.f, 0.f};
    float4 a1 = {0.f, 0.f, 0.f, 0.f};
    #pragma unroll 4
    for (int it = 0; it < 16; ++it) {
        const int r = it * 16 + grp;
        const float* vrow = vbase + (size_t)r * rowstride + lane16 * 8;
        const float4 v0 = *reinterpret_cast<const float4*>(vrow);
        const float4 v1 = *reinterpret_cast<const float4*>(vrow + 4);
        const float p = sc[r];
        a0.x = fmaf(p, v0.x, a0.x);  a0.y = fmaf(p, v0.y, a0.y);
        a0.z = fmaf(p, v0.z, a0.z);  a0.w = fmaf(p, v0.w, a0.w);
        a1.x = fmaf(p, v1.x, a1.x);  a1.y = fmaf(p, v1.y, a1.y);
        a1.z = fmaf(p, v1.z, a1.z);  a1.w = fmaf(p, v1.w, a1.w);
    }
    *reinterpret_cast<float4*>(&partial[grp][lane16 * 8])     = a0;
    *reinterpret_cast<float4*>(&partial[grp][lane16 * 8 + 4]) = a1;
    __syncthreads();

    const size_t base = (size_t)(b * HEAD_NUM + h) * NCHUNK + c;
    if (tid < D_K) {
        float r = 0.f;
        #pragma unroll
        for (int g = 0; g < 16; ++g) r += partial[g][tid];
        part_o[base * D_K + tid] = r;
    }
    if (tid == 0) {
        part_ml[base * 2 + 0] = m;
        part_ml[base * 2 + 1] = sum;
    }
}

// ---------------------------------------------------------------------------
// Kernel 3: combine chunk partials + new-token (s = start_pos) term.
// ---------------------------------------------------------------------------
__global__ __launch_bounds__(128) void combine_kernel(
    const float* __restrict__ qkv,
    const float* __restrict__ part_o,
    const float* __restrict__ part_ml,
    float* __restrict__ attn_out)
{
    const int h   = blockIdx.x;
    const int b   = blockIdx.y;
    const int tid = threadIdx.x;     // 0..127
    __shared__ float redS[2];

    const float* q    = qkv + b * HIDDEN + h * D_K;
    const float* knew = qkv + 1 * (MAX_BS * HIDDEN) + b * HIDDEN + h * D_K;
    const float* vnew = qkv + 2 * (MAX_BS * HIDDEN) + b * HIDDEN + h * D_K;

    float pp = q[tid] * knew[tid];
    #pragma unroll
    for (int off = 32; off; off >>= 1) pp += __shfl_xor(pp, off);
    if ((tid & 63) == 0) redS[tid >> 6] = pp;
    __syncthreads();
    const float score = (redS[0] + redS[1]) * 0.08838834764831845f;

    const size_t base = (size_t)(b * HEAD_NUM + h) * NCHUNK;
    float mv[NCHUNK];
    float M = score;
    #pragma unroll
    for (int c = 0; c < NCHUNK; ++c) {
        mv[c] = part_ml[(base + c) * 2];
        M = fmaxf(M, mv[c]);
    }
    float acc = 0.f, l = 0.f;
    #pragma unroll
    for (int c = 0; c < NCHUNK; ++c) {
        const float w = __expf(mv[c] - M);
        acc += w * part_o[(base + c) * D_K + tid];
        l   += w * part_ml[(base + c) * 2 + 1];
    }
    const float wn = __expf(score - M);
    acc += wn * vnew[tid];
    l   += wn;

    attn_out[b * HIDDEN + h * D_K + tid] = acc / l;
}

// ---------------------------------------------------------------------------
// Kernel 4: out = attn_out @ w_o. Same float4-x-window restructure,
// k-split x32 (512 blocks), atomics into memset-zeroed d_out.
// ---------------------------------------------------------------------------
__global__ __launch_bounds__(256) void oproj_kernel(
    const float* __restrict__ attn_out,
    const float* __restrict__ w_o,
    float* __restrict__ out)
{
    __shared__ float xs[MAX_BS][128];
    const int colTile = blockIdx.x;   // 0..15
    const int kChunk  = blockIdx.y;   // 0..31
    const int tid     = threadIdx.x;

    for (int idx = tid; idx < MAX_BS * 128 / 4; idx += 256) {
        int b = idx >> 5;
        int f = idx & 31;
        *reinterpret_cast<float4*>(&xs[b][f * 4]) =
            *reinterpret_cast<const float4*>(&attn_out[b * HIDDEN + kChunk * 128 + f * 4]);
    }
    __syncthreads();

    const int col = colTile * 256 + tid;
    float acc[MAX_BS];
    #pragma unroll
    for (int b = 0; b < MAX_BS; ++b) acc[b] = 0.f;

    const float* wcol = w_o + (size_t)(kChunk * 128) * HIDDEN + col;
    #pragma unroll 2
    for (int w = 0; w < 128; w += 4) {
        const float w0 = wcol[(size_t)(w + 0) * HIDDEN];
        const float w1 = wcol[(size_t)(w + 1) * HIDDEN];
        const float w2 = wcol[(size_t)(w + 2) * HIDDEN];
        const float w3 = wcol[(size_t)(w + 3) * HIDDEN];
        #pragma unroll
        for (int b = 0; b < MAX_BS; ++b) {
            const float4 xv = *reinterpret_cast<const float4*>(&xs[b][w]);
            acc[b] = fmaf(xv.x, w0, fmaf(xv.y, w1, fmaf(xv.z, w2, fmaf(xv.w, w3, acc[b]))));
        }
    }

    #pragma unroll
    for (int b = 0; b < MAX_BS; ++b)
        atomicAdd(&out[b * HIDDEN + col], acc[b]);
}

extern "C" void kernel_launch(void* const* d_in, const int* in_sizes, int n_in,
                              void* d_out, int out_size, void* d_ws, size_t ws_size,
                              hipStream_t stream) {
    const float* x       = (const float*)d_in[0];
    const float* cache_k = (const float*)d_in[1];
    const float* cache_v = (const float*)d_in[2];
    const float* w_q     = (const float*)d_in[3];
    const float* w_k     = (const float*)d_in[4];
    const float* w_v     = (const float*)d_in[5];
    const float* w_o     = (const float*)d_in[6];
    const int*   start_pos = (const int*)d_in[7];

    float* out      = (float*)d_out;
    float* qkv      = (float*)d_ws;                          // [3][16][4096]
    float* attn_out = qkv + 3 * MAX_BS * HIDDEN;             // [16][4096]
    float* part_o   = attn_out + MAX_BS * HIDDEN;            // [16][32][8][128]
    float* part_ml  = part_o + (size_t)MAX_BS * HEAD_NUM * NCHUNK * D_K; // [16][32][8][2]

    hipMemsetAsync(qkv, 0, (size_t)3 * MAX_BS * HIDDEN * sizeof(float), stream);
    hipMemsetAsync(d_out, 0, (size_t)out_size * sizeof(float), stream);

    qkv_kernel<<<dim3(16, 32, 3), 256, 0, stream>>>(x, w_q, w_k, w_v, qkv);
    attn_partial_kernel<<<dim3(HEAD_NUM, MAX_BS, NCHUNK), 256, 0, stream>>>(
        cache_k, cache_v, qkv, start_pos, part_o, part_ml);
    combine_kernel<<<dim3(HEAD_NUM, MAX_BS), 128, 0, stream>>>(
        qkv, part_o, part_ml, attn_out);
    oproj_kernel<<<dim3(16, 32), 256, 0, stream>>>(attn_out, w_o, out);
}